// Round 3
// baseline (539.129 us; speedup 1.0000x reference)
//
#include <hip/hip_runtime.h>
#include <stdint.h>

#define BB 32
#define CC 256
#define HH 56
#define WW 56
#define TAPS 9
#define NCONV 3
#define PD 58                    // padded rows & cols (1..56 data)
#define PLANE_WORDS (PD * PD)    // 3364 u64
#define NPLANE 12                // (j,g)
#define BN_EPS 1e-5f

// workspace (u64 words unless noted):
//   planes : [n][12][58][58]          = 32*12*3364 = 1,291,776 w (10.33 MB)
//   wbits  : [(j*9+t)*4+g][256 o]     = 27648 w (216 KB)
//   f32: scales[3][256], Cw[27][256], CT[256][8], Epack[256][4]
#define PLANES_WORDS ((size_t)BB * NPLANE * PLANE_WORDS)
#define WBITS_WORDS  ((size_t)NCONV * TAPS * 4 * CC)

// ---------------------------------------------------------------------------
// Kernel 1: pack activation signs -> 12 pre-rolled fully-padded bit planes.
// wave = (n,h,g); lane = w. Pads pre-zeroed by hipMemsetAsync.
// ---------------------------------------------------------------------------
__global__ __launch_bounds__(256) void pack_act_kernel(
    const float* __restrict__ x, const float* __restrict__ bias0,
    uint64_t* __restrict__ planes)
{
    const int lane = threadIdx.x & 63;
    const int wid  = blockIdx.x * 4 + (threadIdx.x >> 6);   // 0 .. 32*56*4-1
    const int g  = wid & 3;
    const int nh = wid >> 2;
    const int h  = nh % HH;
    const int n  = nh / HH;
    const int w  = lane;
    const int wl = (w < WW) ? w : (WW - 1);   // clamp lanes 56..63

    const float* xp = x + ((size_t)(n * CC + g * 64) * HH + h) * WW;
    uint32_t mlo = 0u, mhi = 0u;
    #pragma unroll
    for (int c = 0; c < 32; ++c) {
        float v = xp[(size_t)c * (HH * WW) + wl] + bias0[g * 64 + c];
        mlo |= (v > 0.f ? 1u : 0u) << c;
    }
    #pragma unroll
    for (int c = 0; c < 32; ++c) {
        float v = xp[(size_t)(c + 32) * (HH * WW) + wl] + bias0[g * 64 + c + 32];
        mhi |= (v > 0.f ? 1u : 0u) << c;
    }
    const uint64_t m = ((uint64_t)mhi << 32) | (uint64_t)mlo;

    if (w < WW) {
        #pragma unroll 1
        for (int j = 0; j < NCONV; ++j) {
            const int amt = (j == 0) ? 0 : ((j == 1) ? 1 : 3);
            const int AH = (g == 0) ? amt : ((g == 1) ? -amt : 0);
            const int AW = (g == 2) ? amt : ((g == 3) ? -amt : 0);
            int row = h + AH; if (row < 0) row += HH; else if (row >= HH) row -= HH;
            int col = w + AW; if (col < 0) col += WW; else if (col >= WW) col -= WW;
            planes[(size_t)(n * NPLANE + j * 4 + g) * PLANE_WORDS
                   + (row + 1) * PD + (col + 1)] = m;
        }
    }
}

// ---------------------------------------------------------------------------
// Kernel 2: weight sign words (o-contiguous for SMEM), scales, Cw constants.
// one wave per (j,o).
// ---------------------------------------------------------------------------
__global__ __launch_bounds__(64) void pack_w_kernel(
    const float* __restrict__ w0, const float* __restrict__ w1,
    const float* __restrict__ w2,
    uint64_t* __restrict__ wbits, float* __restrict__ scales,
    float* __restrict__ Cw)
{
    const int j = blockIdx.x >> 8;          // 0..2
    const int o = blockIdx.x & 255;
    const float* wp = (j == 0) ? w0 : ((j == 1) ? w1 : w2);
    const int lane = threadIdx.x;           // 0..63

    const float* wo = wp + (size_t)o * CC * TAPS;
    float s = 0.f;
    for (int k = lane; k < CC * TAPS; k += 64) s += fabsf(wo[k]);
    #pragma unroll
    for (int d = 32; d > 0; d >>= 1) s += __shfl_xor(s, d);
    if (lane == 0) scales[j * CC + o] = s * (1.0f / (float)(CC * TAPS));

    for (int t = 0; t < TAPS; ++t) {
        int pcsum = 0;
        #pragma unroll
        for (int g = 0; g < 4; ++g) {
            float v = wp[((size_t)o * CC + g * 64 + lane) * TAPS + t];
            uint64_t m = __ballot(v > 0.0f);
            pcsum += (int)__popcll(m);
            if (lane == 0)
                wbits[(size_t)((j * TAPS + t) * 4 + g) * CC + o] = m;
        }
        if (lane == 0) Cw[(j * TAPS + t) * CC + o] = (float)(256 - 2 * pcsum);
    }
}

// ---------------------------------------------------------------------------
// Kernel 3: fold scales into pad-correction terms CT[o][8] and epilogue
// constants Epack[o][4] = {A, B, prelu_a, bias2}.  one thread per o.
// ---------------------------------------------------------------------------
__global__ __launch_bounds__(256) void pack_corr_kernel(
    const float* __restrict__ scales, const float* __restrict__ Cw,
    const float* __restrict__ gamma, const float* __restrict__ beta,
    const float* __restrict__ rmean, const float* __restrict__ rvar,
    const float* __restrict__ bias1, const float* __restrict__ prelu_a,
    const float* __restrict__ bias2,
    float* __restrict__ CT, float* __restrict__ Epack)
{
    const int o = threadIdx.x;
    float row0 = 0.f, row2 = 0.f, col0 = 0.f, col2 = 0.f;
    float c00 = 0.f, c02 = 0.f, c20 = 0.f, c22 = 0.f;
    for (int j = 0; j < NCONV; ++j) {
        const float sc = scales[j * CC + o];
        const float* cw = Cw + j * TAPS * CC;
        float t0 = cw[0 * CC + o], t1 = cw[1 * CC + o], t2 = cw[2 * CC + o];
        float t3 = cw[3 * CC + o], t5 = cw[5 * CC + o];
        float t6 = cw[6 * CC + o], t7 = cw[7 * CC + o], t8 = cw[8 * CC + o];
        row0 += sc * (t0 + t1 + t2);
        row2 += sc * (t6 + t7 + t8);
        col0 += sc * (t0 + t3 + t6);
        col2 += sc * (t2 + t5 + t8);
        c00 += sc * t0; c02 += sc * t2; c20 += sc * t6; c22 += sc * t8;
    }
    CT[o * 8 + 0] = row0;  CT[o * 8 + 1] = row2;
    CT[o * 8 + 2] = col0;  CT[o * 8 + 3] = col2;
    CT[o * 8 + 4] = -c00;  CT[o * 8 + 5] = -c02;
    CT[o * 8 + 6] = -c20;  CT[o * 8 + 7] = -c22;

    const float A = gamma[o] * rsqrtf(rvar[o] + BN_EPS);
    Epack[o * 4 + 0] = A;
    Epack[o * 4 + 1] = beta[o] - rmean[o] * A + bias1[o];
    Epack[o * 4 + 2] = prelu_a[o];
    Epack[o * 4 + 3] = bias2[o];
}

// ---------------------------------------------------------------------------
// Kernel 4: binary conv x3 + BN + residual + PReLU.  lane = pixel.
// block = (n, q): 4 waves = 4 o-splits of 64 channels over the same 64 px.
// Inner loop: 9 always-valid taps x 4 groups: 1 per-lane dwordx2 (act word,
// imm-offset addressed) + 16 uniform weight words (SMEM) + 64 xor/bcnt.
// Pad contributions removed exactly via CT masks in the epilogue.
// ---------------------------------------------------------------------------
__global__ __launch_bounds__(256) void conv_main_kernel(
    const uint64_t* __restrict__ planes, const uint64_t* __restrict__ wbits,
    const float* __restrict__ scales, const float* __restrict__ CT,
    const float* __restrict__ Epack, const float* __restrict__ x,
    float* __restrict__ out)
{
    const int lane   = threadIdx.x & 63;
    const int osplit = __builtin_amdgcn_readfirstlane(threadIdx.x >> 6); // 0..3
    const int blk = blockIdx.x;             // n*49 + q
    const int q = blk % 49;
    const int n = blk / 49;
    const int p = q * 64 + lane;            // flat pixel 0..3135
    const int h = p / WW, w = p % WW;
    const int vpix = (h + 1) * PD + (w + 1);

    // edge masks (pad-correction selectors)
    const float mr0 = (h == 0) ? 1.f : 0.f, mr2 = (h == HH - 1) ? 1.f : 0.f;
    const float mc0 = (w == 0) ? 1.f : 0.f, mc2 = (w == WW - 1) ? 1.f : 0.f;
    const float m00 = mr0 * mc0, m02 = mr0 * mc2;
    const float m20 = mr2 * mc0, m22 = mr2 * mc2;

    const size_t xbase = (size_t)n * CC * (HH * WW);

    #pragma unroll 1
    for (int oti = 0; oti < 4; ++oti) {
        const int ob = osplit * 64 + oti * 16;
        float fsum[16];
        #pragma unroll
        for (int i = 0; i < 16; ++i) fsum[i] = 0.f;

        #pragma unroll 1
        for (int j = 0; j < NCONV; ++j) {
            uint32_t acc[16];
            #pragma unroll
            for (int i = 0; i < 16; ++i) acc[i] = 0u;

            #pragma unroll 1
            for (int ty = 0; ty < 3; ++ty) {
                #pragma unroll 1
                for (int tx = 0; tx < 3; ++tx) {
                    const int t = ty * 3 + tx;
                    #pragma unroll
                    for (int g = 0; g < 4; ++g) {
                        const uint64_t* pl = planes +
                            (size_t)(n * NPLANE + j * 4 + g) * PLANE_WORDS;
                        const uint64_t a = pl[vpix + (ty - 1) * PD + (tx - 1)];
                        const uint32_t alo = (uint32_t)a;
                        const uint32_t ahi = (uint32_t)(a >> 32);
                        const uint64_t* wrow = wbits +
                            (size_t)((j * TAPS + t) * 4 + g) * CC + ob;
                        #pragma unroll
                        for (int i = 0; i < 16; ++i) {
                            const uint64_t wv = wrow[i];   // uniform -> SMEM
                            acc[i] += __popc(alo ^ (uint32_t)wv);
                            acc[i] += __popc(ahi ^ (uint32_t)(wv >> 32));
                        }
                    }
                }
            }
            const float* scj = scales + j * CC + ob;       // uniform
            #pragma unroll
            for (int i = 0; i < 16; ++i)
                fsum[i] += scj[i] * (2304.f - 2.f * (float)acc[i]);
        }

        // pad correction + BN + residual + PReLU epilogue
        #pragma unroll
        for (int i = 0; i < 16; ++i) {
            const int o = ob + i;
            const float* ct = CT + o * 8;                  // uniform
            const float corr = mr0 * ct[0] + mr2 * ct[1] + mc0 * ct[2]
                             + mc2 * ct[3] + m00 * ct[4] + m02 * ct[5]
                             + m20 * ct[6] + m22 * ct[7];
            const float fs = fsum[i] - corr;
            const float* ep = Epack + o * 4;               // uniform
            const size_t off = xbase + (size_t)o * (HH * WW) + p;
            float v = fs * ep[0] + ep[1] + x[off];
            v = (v > 0.f) ? v : ep[2] * v;
            out[off] = v + ep[3];
        }
    }
}

// ---------------------------------------------------------------------------
extern "C" void kernel_launch(void* const* d_in, const int* in_sizes, int n_in,
                              void* d_out, int out_size, void* d_ws, size_t ws_size,
                              hipStream_t stream) {
    const float* x       = (const float*)d_in[0];
    const float* bias0   = (const float*)d_in[1];
    const float* w0      = (const float*)d_in[2];
    const float* w1      = (const float*)d_in[3];
    const float* w2      = (const float*)d_in[4];
    const float* gamma   = (const float*)d_in[5];
    const float* beta    = (const float*)d_in[6];
    const float* rmean   = (const float*)d_in[7];
    const float* rvar    = (const float*)d_in[8];
    const float* bias1   = (const float*)d_in[9];
    const float* prelu_a = (const float*)d_in[10];
    const float* bias2   = (const float*)d_in[11];
    float* out = (float*)d_out;

    uint64_t* planes = (uint64_t*)d_ws;
    uint64_t* wbits  = planes + PLANES_WORDS;
    float*    scales = (float*)(wbits + WBITS_WORDS);
    float*    Cw     = scales + NCONV * CC;           // 27*256
    float*    CT     = Cw + NCONV * TAPS * CC;        // 256*8
    float*    Epack  = CT + CC * 8;                   // 256*4

    // zero pad frames (pack_act writes only data cells)
    hipMemsetAsync(planes, 0, PLANES_WORDS * sizeof(uint64_t), stream);

    pack_act_kernel<<<dim3(BB * HH * 4 / 4), dim3(256), 0, stream>>>(x, bias0, planes);
    pack_w_kernel<<<dim3(NCONV * CC), dim3(64), 0, stream>>>(w0, w1, w2, wbits, scales, Cw);
    pack_corr_kernel<<<dim3(1), dim3(256), 0, stream>>>(
        scales, Cw, gamma, beta, rmean, rvar, bias1, prelu_a, bias2, CT, Epack);
    conv_main_kernel<<<dim3(BB * 49), dim3(256), 0, stream>>>(
        planes, wbits, scales, CT, Epack, x, out);
}

// Round 5
// 428.662 us; speedup vs baseline: 1.2577x; 1.2577x over previous
//
#include <hip/hip_runtime.h>
#include <stdint.h>

#define BB 32
#define CC 256
#define HH 56
#define WW 56
#define TAPS 9
#define NCONV 3
#define BN_EPS 1e-5f

typedef int int4v  __attribute__((ext_vector_type(4)));
typedef int int16v __attribute__((ext_vector_type(16)));

// v_mfma_i32_32x32x32_i8: A 4 VGPR (16 i8), B 4 VGPR, C/D 16 VGPR.
#define MFMA_I8(accv, av, bv) \
    asm("v_mfma_i32_32x32x32_i8 %0, %1, %2, %0" : "+v"(accv) : "v"(av), "v"(bv))

// ---------------- workspace layout (bytes) ----------------
// act8  : [n][56][56][256] i8 sign            = 25,690,112
// wpack : [j][ot(8)][g(4)][t(9)][ch(2)][lane(64)][16] i8 = 1,769,472
// scales: [3][256] f32
// epack : [256][4] f32
#define ACT8_BYTES   ((size_t)BB * HH * WW * CC)
#define WPACK_BYTES  ((size_t)NCONV * 8 * 4 * TAPS * 2 * 64 * 16)

#define LDS_PXSTRIDE 80                       // 64B data + 16B pad (16B-aligned)
#define LDS_ROWSTRIDE (58 * LDS_PXSTRIDE)     // 4640
#define LDS_BYTES (5 * LDS_ROWSTRIDE)         // 23200

// act8[n][h][w][c] = sign(x + bias0) in i8 (-1/0/+1). LDS transpose so both
// global read (lane=w) and global write (c-contiguous dwords) are coalesced.
__global__ __launch_bounds__(256) void pack_act8_kernel(
    const float* __restrict__ x, const float* __restrict__ bias0,
    int8_t* __restrict__ act8)
{
    __shared__ int8_t ldsT[56 * 260];
    const int tid = threadIdx.x;
    const int h = blockIdx.x % HH, n = blockIdx.x / HH;
    const int w = tid & 63;
    const int cq = tid >> 6;
    if (w < WW) {
        #pragma unroll 4
        for (int cc = 0; cc < 64; ++cc) {
            const int c = cc * 4 + cq;
            const float v = x[((size_t)(n * CC + c) * HH + h) * WW + w] + bias0[c];
            ldsT[w * 260 + c] = (v > 0.f) ? (int8_t)1 : ((v < 0.f) ? (int8_t)-1 : (int8_t)0);
        }
    }
    __syncthreads();
    uint32_t* o32 = (uint32_t*)(act8 + (size_t)(n * HH + h) * WW * CC);
    #pragma unroll
    for (int i = 0; i < 14; ++i) {
        const int flat = i * 1024 + tid * 4;            // byte index, 56*256 total
        const int ww = flat >> 8, c4 = flat & 255;
        o32[flat >> 2] = *(const uint32_t*)(ldsT + ww * 260 + c4);
    }
}

// per-output-channel scale = mean |w|. one wave per (j,o).
__global__ __launch_bounds__(64) void pack_scales_kernel(
    const float* __restrict__ w0, const float* __restrict__ w1,
    const float* __restrict__ w2, float* __restrict__ scales)
{
    const int j = blockIdx.x >> 8;
    const int o = blockIdx.x & 255;
    const float* wp = (j == 0) ? w0 : ((j == 1) ? w1 : w2);
    const int lane = threadIdx.x;
    const float* wo = wp + (size_t)o * CC * TAPS;
    float s = 0.f;
    for (int k = lane; k < CC * TAPS; k += 64) s += fabsf(wo[k]);
    #pragma unroll
    for (int d = 32; d > 0; d >>= 1) s += __shfl_xor(s, d);
    if (lane == 0) scales[j * CC + o] = s * (1.0f / (float)(CC * TAPS));
}

// weight signs in exact A-fragment order:
// wpack[((j*8+ot)*4+g)*18 + t*2+ch][lane][16B]; lane: o=ot*32+(lane&31),
// byte b: c = g*64 + ch*32 + (lane>>5)*16 + b.
__global__ __launch_bounds__(256) void pack_wpack_kernel(
    const float* __restrict__ w0, const float* __restrict__ w1,
    const float* __restrict__ w2, int8_t* __restrict__ wpack)
{
    const int j  = blockIdx.x >> 3;
    const int ot = blockIdx.x & 7;
    const float* wp = (j == 0) ? w0 : ((j == 1) ? w1 : w2);
    const int tid = threadIdx.x;
    #pragma unroll 1
    for (int it = 0; it < 18; ++it) {
        const int e = it * 256 + tid;          // 0..4607
        const int g = e / 1152;
        const int rem = e - g * 1152;
        const int tt = rem >> 7;               // /128
        const int rem2 = rem & 127;
        const int ch = rem2 >> 6;
        const int ln = rem2 & 63;
        const int o = ot * 32 + (ln & 31);
        const int cbase = g * 64 + ch * 32 + ((ln >> 5) & 1) * 16;
        int8_t bytes[16];
        #pragma unroll
        for (int b = 0; b < 16; ++b) {
            const float v = wp[((size_t)o * CC + cbase + b) * TAPS + tt];
            bytes[b] = (v > 0.f) ? (int8_t)1 : ((v < 0.f) ? (int8_t)-1 : (int8_t)0);
        }
        *(int4v*)(wpack + ((size_t)(j * 8 + ot) * 4608 + e) * 16) = *(int4v*)bytes;
    }
}

// epilogue constants per o: {A, beta - rmean*A + bias1, prelu_a, bias2}
__global__ __launch_bounds__(256) void pack_epack_kernel(
    const float* __restrict__ gamma, const float* __restrict__ beta,
    const float* __restrict__ rmean, const float* __restrict__ rvar,
    const float* __restrict__ bias1, const float* __restrict__ prelu_a,
    const float* __restrict__ bias2, float* __restrict__ epack)
{
    const int o = threadIdx.x;
    const float A = gamma[o] * rsqrtf(rvar[o] + BN_EPS);
    epack[o * 4 + 0] = A;
    epack[o * 4 + 1] = beta[o] - rmean[o] * A + bias1[o];
    epack[o * 4 + 2] = prelu_a[o];
    epack[o * 4 + 3] = bias2[o];
}

// main: i8 MFMA implicit conv. block = (n, 64-px strip); 4 waves = 4 o-slices.
// per (j,g) phase: stage rolled+padded 5x58x64B act tile into LDS (GATHER:
// dest[i] = src[i - amt] for roll(+amt)), then 18 k-steps x {2 A dwordx4,
// 2 B ds_read_b128, 4 mfma}. fold per-j with scales; epilogue fused.
__global__ __launch_bounds__(256) void conv_mfma_kernel(
    const int8_t* __restrict__ act8, const int8_t* __restrict__ wpack,
    const float* __restrict__ scales, const float* __restrict__ epack,
    const float* __restrict__ x, float* __restrict__ out)
{
    __shared__ __align__(16) int8_t lds[LDS_BYTES];
    const int tid  = threadIdx.x;
    const int lane = tid & 63;
    const int wv   = __builtin_amdgcn_readfirstlane(tid >> 6);
    const int pxblk = blockIdx.x % 49;
    const int n     = blockIdx.x / 49;
    const int px0   = pxblk * 64;
    const int h_lo  = px0 / WW;

    // per-lane LDS byte bases for the two B px-tiles (includes -row-col bias)
    int ldsoff[2];
    #pragma unroll
    for (int pt = 0; pt < 2; ++pt) {
        const int p = px0 + pt * 32 + (lane & 31);
        const int hl = p / WW, wl = p % WW;
        ldsoff[pt] = (hl - h_lo + 1) * LDS_ROWSTRIDE + (wl + 1) * LDS_PXSTRIDE
                   + ((lane >> 5) & 1) * 16 - (LDS_ROWSTRIDE + LDS_PXSTRIDE);
    }

    float fsum[2][2][16];
    #pragma unroll
    for (int q = 0; q < 2; ++q)
        #pragma unroll
        for (int pt = 0; pt < 2; ++pt)
            #pragma unroll
            for (int r = 0; r < 16; ++r) fsum[q][pt][r] = 0.f;

    #pragma unroll 1
    for (int j = 0; j < NCONV; ++j) {
        const int amt = (j == 0) ? 0 : ((j == 1) ? 1 : 3);
        int16v acc[2][2];
        #pragma unroll
        for (int q = 0; q < 2; ++q)
            #pragma unroll
            for (int pt = 0; pt < 2; ++pt)
                #pragma unroll
                for (int r = 0; r < 16; ++r) acc[q][pt][r] = 0;

        #pragma unroll 1
        for (int g = 0; g < 4; ++g) {
            // GATHER roll: roll(+amt) -> read src at (idx - amt) mod N
            const int rH = (g == 0) ? -amt : ((g == 1) ? amt : 0);
            const int rW = (g == 2) ? -amt : ((g == 3) ? amt : 0);
            __syncthreads();
            for (int u = tid; u < 5 * 58 * 8; u += 256) {
                const int r = u / 464;
                const int rem = u - r * 464;
                const int c = rem >> 3, b8 = rem & 7;
                const int hr = h_lo - 1 + r, wc = c - 1;
                uint64_t v = 0ull;
                if (hr >= 0 && hr < HH && wc >= 0 && wc < WW) {
                    int hs = hr + rH; if (hs < 0) hs += HH; else if (hs >= HH) hs -= HH;
                    int ws = wc + rW; if (ws < 0) ws += WW; else if (ws >= WW) ws -= WW;
                    v = *(const uint64_t*)(act8 +
                        (((size_t)(n * HH + hs) * WW + ws) << 8) + g * 64 + b8 * 8);
                }
                *(uint64_t*)(lds + r * LDS_ROWSTRIDE + c * LDS_PXSTRIDE + b8 * 8) = v;
            }
            __syncthreads();

            const int8_t* wbase = wpack
                + ((size_t)((j * 8 + wv * 2) * 4 + g) * 18) * 1024 + lane * 16;
            #pragma unroll
            for (int t = 0; t < TAPS; ++t) {
                #pragma unroll
                for (int ch = 0; ch < 2; ++ch) {
                    const int koff = (t * 2 + ch) * 1024;
                    const int4v a0 = *(const int4v*)(wbase + koff);
                    const int4v a1 = *(const int4v*)(wbase + 73728 + koff);
                    const int ldsimm = ((t / 3) * 58 + (t % 3)) * LDS_PXSTRIDE + ch * 32;
                    const int4v b0 = *(const int4v*)(lds + ldsoff[0] + ldsimm);
                    const int4v b1 = *(const int4v*)(lds + ldsoff[1] + ldsimm);
                    MFMA_I8(acc[0][0], a0, b0);
                    MFMA_I8(acc[0][1], a0, b1);
                    MFMA_I8(acc[1][0], a1, b0);
                    MFMA_I8(acc[1][1], a1, b1);
                }
            }
        }

        // fold: fsum += s_j[o] * acc  (o = wv*64 + q*32 + (r&3)+8*(r>>2)+4*(lane>>5))
        const float* scj = scales + j * CC + wv * 64;
        #pragma unroll
        for (int q = 0; q < 2; ++q) {
            #pragma unroll
            for (int r = 0; r < 16; ++r) {
                const int rb = q * 32 + (r & 3) + 8 * (r >> 2);
                const float slo = scj[rb], shi = scj[rb + 4];
                const float sc = (lane & 32) ? shi : slo;
                fsum[q][0][r] += sc * (float)acc[q][0][r];
                fsum[q][1][r] += sc * (float)acc[q][1][r];
            }
        }
    }

    // epilogue
    const int voff = (lane & 31) + ((lane >> 5) & 1) * (4 * HH * WW);
    #pragma unroll
    for (int q = 0; q < 2; ++q) {
        #pragma unroll
        for (int r = 0; r < 16; ++r) {
            const int o_lo = wv * 64 + q * 32 + (r & 3) + 8 * (r >> 2);
            const float* elo = epack + o_lo * 4;
            const float* ehi = epack + (o_lo + 4) * 4;
            const bool hi = (lane & 32) != 0;
            const float e0 = hi ? ehi[0] : elo[0];
            const float e1 = hi ? ehi[1] : elo[1];
            const float e2 = hi ? ehi[2] : elo[2];
            const float e3 = hi ? ehi[3] : elo[3];
            const size_t base = ((size_t)n * CC + o_lo) * (HH * WW) + px0;
            #pragma unroll
            for (int pt = 0; pt < 2; ++pt) {
                const size_t off = base + pt * 32 + voff;
                float v = fsum[q][pt][r] * e0 + e1 + x[off];
                v = (v > 0.f) ? v : e2 * v;
                out[off] = v + e3;
            }
        }
    }
}

// ===========================================================================
extern "C" void kernel_launch(void* const* d_in, const int* in_sizes, int n_in,
                              void* d_out, int out_size, void* d_ws, size_t ws_size,
                              hipStream_t stream) {
    const float* x       = (const float*)d_in[0];
    const float* bias0   = (const float*)d_in[1];
    const float* w0      = (const float*)d_in[2];
    const float* w1      = (const float*)d_in[3];
    const float* w2      = (const float*)d_in[4];
    const float* gamma   = (const float*)d_in[5];
    const float* beta    = (const float*)d_in[6];
    const float* rmean   = (const float*)d_in[7];
    const float* rvar    = (const float*)d_in[8];
    const float* bias1   = (const float*)d_in[9];
    const float* prelu_a = (const float*)d_in[10];
    const float* bias2   = (const float*)d_in[11];
    float* out = (float*)d_out;

    int8_t* act8   = (int8_t*)d_ws;
    int8_t* wpack  = act8 + ACT8_BYTES;
    float*  scales = (float*)(wpack + WPACK_BYTES);
    float*  epack  = scales + NCONV * CC;

    pack_act8_kernel<<<dim3(BB * HH), dim3(256), 0, stream>>>(x, bias0, act8);
    pack_scales_kernel<<<dim3(NCONV * CC), dim3(64), 0, stream>>>(w0, w1, w2, scales);
    pack_wpack_kernel<<<dim3(NCONV * 8), dim3(256), 0, stream>>>(w0, w1, w2, wpack);
    pack_epack_kernel<<<dim3(1), dim3(256), 0, stream>>>(
        gamma, beta, rmean, rvar, bias1, prelu_a, bias2, epack);
    conv_mfma_kernel<<<dim3(BB * 49), dim3(256), 0, stream>>>(
        act8, wpack, scales, epack, x, out);
}